// Round 5
// baseline (781.593 us; speedup 1.0000x reference)
//
#include <hip/hip_runtime.h>
#include <hip/hip_bf16.h>
#include <math.h>

// ---------------------------------------------------------------------------
// MPNN node classifier.
// R4: XCD-partitioned CSR build (fill wrote 101MB HBM for 6.4MB logical due
// to cross-XCD line thrash -> partition dst ranges by blockIdx%8), feature-
// sliced gather (32-feature slices -> 3.2MB/XCD working set, L2-resident),
// int4 scan. Partitioning is a perf heuristic only; correctness unaffected.
// ---------------------------------------------------------------------------

#define F_DIM 256   // F_IN == H == 256
#define C_DIM 40
#define NPART 8

typedef _Float16 half8 __attribute__((ext_vector_type(8)));
typedef _Float16 half4 __attribute__((ext_vector_type(4)));
typedef _Float16 half2v __attribute__((ext_vector_type(2)));
typedef float    f32x4 __attribute__((ext_vector_type(4)));

// --- convert + transpose weight: w[k][n] fp32 -> wt[n][k] fp16  (256x256)
__global__ __launch_bounds__(256) void cvt_wT(
    const float* __restrict__ w, _Float16* __restrict__ wt)
{
    const int n = threadIdx.x;
    const int k = blockIdx.x;
    wt[n * 256 + k] = (_Float16)w[k * 256 + n];
}

// --- convert + transpose + pad FC weight: wfc[k][40] fp32 -> wt[48][256] fp16
__global__ __launch_bounds__(48) void cvt_wfc(
    const float* __restrict__ wfc, _Float16* __restrict__ wt)
{
    const int n = threadIdx.x;   // 0..47
    const int k = blockIdx.x;    // 0..255
    wt[n * 256 + k] = (n < C_DIM) ? (_Float16)wfc[k * C_DIM + n] : (_Float16)0.f;
}

// --- MFMA fp16 GEMM: out[M x 256] = f16(relu(A[M x 256] @ Wt^T + bias))
template <bool AF32>
__global__ __launch_bounds__(256, 2) void gemm_f16(
    const void* __restrict__ Av, const _Float16* __restrict__ Wt,
    const float* __restrict__ bias, _Float16* __restrict__ out, int M)
{
    constexpr int K = 256;
    constexpr int LDA = 40;                 // padded fp16 stride: 2-way-free banks
    __shared__ _Float16 As[128 * LDA];
    __shared__ _Float16 Bs[64 * LDA];

    const int tid  = threadIdx.x;
    const int wave = tid >> 6;
    const int lane = tid & 63;
    const int quad = lane >> 4;
    const int l16  = lane & 15;
    const int row0 = blockIdx.x * 128;
    const int col0 = blockIdx.y * 64;

    f32x4 acc[2][4] = {};

    for (int k0 = 0; k0 < K; k0 += 32) {
        #pragma unroll
        for (int c = tid; c < 512; c += 256) {
            const int r  = c >> 2;
            const int ko = (c & 3) * 8;
            const int gr = row0 + r;
            half8 v = {};
            if (gr < M) {
                if constexpr (AF32) {
                    const float* A = (const float*)Av;
                    const float4 u0 = *(const float4*)(A + (size_t)gr * K + k0 + ko);
                    const float4 u1 = *(const float4*)(A + (size_t)gr * K + k0 + ko + 4);
                    v[0] = (_Float16)u0.x; v[1] = (_Float16)u0.y;
                    v[2] = (_Float16)u0.z; v[3] = (_Float16)u0.w;
                    v[4] = (_Float16)u1.x; v[5] = (_Float16)u1.y;
                    v[6] = (_Float16)u1.z; v[7] = (_Float16)u1.w;
                } else {
                    const _Float16* A = (const _Float16*)Av;
                    v = *(const half8*)(A + (size_t)gr * K + k0 + ko);
                }
            }
            *(half8*)&As[r * LDA + ko] = v;
        }
        {
            const int n  = tid >> 2;
            const int ko = (tid & 3) * 8;
            const half8 v = *(const half8*)(Wt + (size_t)(col0 + n) * K + k0 + ko);
            *(half8*)&Bs[n * LDA + ko] = v;
        }
        __syncthreads();

        half8 af[2], bf[4];
        #pragma unroll
        for (int mi = 0; mi < 2; ++mi)
            af[mi] = *(const half8*)&As[(wave * 32 + mi * 16 + l16) * LDA + quad * 8];
        #pragma unroll
        for (int ni = 0; ni < 4; ++ni)
            bf[ni] = *(const half8*)&Bs[(ni * 16 + l16) * LDA + quad * 8];
        #pragma unroll
        for (int mi = 0; mi < 2; ++mi)
            #pragma unroll
            for (int ni = 0; ni < 4; ++ni)
                acc[mi][ni] = __builtin_amdgcn_mfma_f32_16x16x32_f16(
                    af[mi], bf[ni], acc[mi][ni], 0, 0, 0);
        __syncthreads();
    }

    // epilogue: C/D layout col=lane&15, row=quad*4+reg
    #pragma unroll
    for (int ni = 0; ni < 4; ++ni) {
        const int col = col0 + ni * 16 + l16;
        const float b = bias[col];
        #pragma unroll
        for (int mi = 0; mi < 2; ++mi) {
            #pragma unroll
            for (int r = 0; r < 4; ++r) {
                const int grow = row0 + wave * 32 + mi * 16 + quad * 4 + r;
                if (grow < M) {
                    const float v = fmaxf(acc[mi][ni][r] + b, 0.f);
                    out[(size_t)grow * K + col] = (_Float16)v;
                }
            }
        }
    }
}

// --- MFMA FC: logits[M x 40] = h[M x 256] @ wfcT^T + bfc  (no relu)
__global__ __launch_bounds__(256, 2) void fc_mfma(
    const _Float16* __restrict__ h, const _Float16* __restrict__ WfcT,
    const float* __restrict__ bfc, float* __restrict__ logits, int M)
{
    constexpr int K = 256;
    constexpr int LDA = 40;
    constexpr int LDB = 264;
    __shared__ _Float16 As[128 * LDA];
    __shared__ _Float16 Bs[48 * LDB];

    const int tid  = threadIdx.x;
    const int wave = tid >> 6;
    const int lane = tid & 63;
    const int quad = lane >> 4;
    const int l16  = lane & 15;
    const int row0 = blockIdx.x * 128;

    #pragma unroll
    for (int c = tid; c < 1536; c += 256) {
        const int n  = c >> 5;
        const int ko = (c & 31) * 8;
        *(half8*)&Bs[n * LDB + ko] = *(const half8*)(WfcT + (size_t)n * K + ko);
    }

    f32x4 acc[2][3] = {};

    for (int k0 = 0; k0 < K; k0 += 32) {
        #pragma unroll
        for (int c = tid; c < 512; c += 256) {
            const int r  = c >> 2;
            const int ko = (c & 3) * 8;
            const int gr = row0 + r;
            half8 v = {};
            if (gr < M) v = *(const half8*)(h + (size_t)gr * K + k0 + ko);
            *(half8*)&As[r * LDA + ko] = v;
        }
        __syncthreads();

        half8 af[2], bf[3];
        #pragma unroll
        for (int mi = 0; mi < 2; ++mi)
            af[mi] = *(const half8*)&As[(wave * 32 + mi * 16 + l16) * LDA + quad * 8];
        #pragma unroll
        for (int ni = 0; ni < 3; ++ni)
            bf[ni] = *(const half8*)&Bs[(ni * 16 + l16) * LDB + k0 + quad * 8];
        #pragma unroll
        for (int mi = 0; mi < 2; ++mi)
            #pragma unroll
            for (int ni = 0; ni < 3; ++ni)
                acc[mi][ni] = __builtin_amdgcn_mfma_f32_16x16x32_f16(
                    af[mi], bf[ni], acc[mi][ni], 0, 0, 0);
        __syncthreads();
    }

    #pragma unroll
    for (int ni = 0; ni < 3; ++ni) {
        const int col = ni * 16 + l16;
        if (col >= C_DIM) continue;
        const float b = bfc[col];
        #pragma unroll
        for (int mi = 0; mi < 2; ++mi) {
            #pragma unroll
            for (int r = 0; r < 4; ++r) {
                const int grow = row0 + wave * 32 + mi * 16 + quad * 4 + r;
                if (grow < M)
                    logits[(size_t)grow * C_DIM + col] = acc[mi][ni][r] + b;
            }
        }
    }
}

// --- CSR build step 1: degree histogram, XCD-partitioned by dst range
__global__ __launch_bounds__(256) void count_deg_part(
    const int* __restrict__ dst, int* __restrict__ deg, int E, int partSize)
{
    const int part  = blockIdx.x & (NPART - 1);
    const int chunk = blockIdx.x >> 3;
    const int i = chunk * 256 + threadIdx.x;
    if (i >= E) return;
    const int d = dst[i];
    const int lo = part * partSize;
    if (d < lo || d >= lo + partSize) return;
    atomicAdd(&deg[d], 1);
}

// --- CSR build step 2: exclusive scan, int4 per thread (single workgroup)
__global__ __launch_bounds__(1024) void scan_deg4(
    const int* __restrict__ deg, int* __restrict__ rowptr, int N)
{
    __shared__ int waveSums[16];
    __shared__ int carrySh;
    const int tid  = threadIdx.x;
    const int lane = tid & 63;
    const int wid  = tid >> 6;
    const int N4 = N >> 2;                  // N divisible by 4
    if (tid == 0) carrySh = 0;
    __syncthreads();
    for (int base = 0; base < N4; base += 1024) {
        const int i4 = base + tid;
        int4 v = make_int4(0, 0, 0, 0);
        if (i4 < N4) v = ((const int4*)deg)[i4];
        const int tsum = v.x + v.y + v.z + v.w;
        int s = tsum;
        #pragma unroll
        for (int off = 1; off < 64; off <<= 1) {
            const int t = __shfl_up(s, off, 64);
            if (lane >= off) s += t;
        }
        if (lane == 63) waveSums[wid] = s;
        __syncthreads();
        if (wid == 0) {
            const int ws = (lane < 16) ? waveSums[lane] : 0;
            int ss = ws;
            #pragma unroll
            for (int off = 1; off < 16; off <<= 1) {
                const int t = __shfl_up(ss, off, 64);
                if (lane >= off) ss += t;
            }
            if (lane < 16) waveSums[lane] = ss - ws;   // exclusive
        }
        __syncthreads();
        const int carry = carrySh;
        if (i4 < N4) {
            const int e0 = carry + waveSums[wid] + (s - tsum);
            int4 o;
            o.x = e0;
            o.y = e0 + v.x;
            o.z = e0 + v.x + v.y;
            o.w = e0 + v.x + v.y + v.z;
            ((int4*)rowptr)[i4] = o;
        }
        __syncthreads();
        if (tid == 1023) carrySh = carry + waveSums[15] + s;
        __syncthreads();
    }
    if (tid == 0) rowptr[N] = carrySh;
}

// --- CSR build step 3: scatter src ids, XCD-partitioned by dst range
__global__ __launch_bounds__(256) void fill_csr_part(
    const int* __restrict__ src, const int* __restrict__ dst,
    int* __restrict__ cursor, int* __restrict__ csr_src, int E, int partSize)
{
    const int part  = blockIdx.x & (NPART - 1);
    const int chunk = blockIdx.x >> 3;
    const int i = chunk * 256 + threadIdx.x;
    if (i >= E) return;
    const int d = dst[i];
    const int lo = part * partSize;
    if (d < lo || d >= lo + partSize) return;
    const int pos = atomicAdd(&cursor[d], 1);
    csr_src[pos] = src[i];
}

// --- conv aggregate, feature-sliced (32 features = one 64B line per visit):
//     slice = blockIdx%8 -> per-XCD working set 3.2MB (L2-resident).
//     4 waves/block, 4 rows/wave (16 lanes each, 2 features/lane).
//     h[row] = f16(relu(msg[row] + sum_{in-edges} msg[src]))
__global__ __launch_bounds__(256) void csr_gather_sliced(
    const _Float16* __restrict__ msg, const int* __restrict__ rowptr,
    const int* __restrict__ csr_src, _Float16* __restrict__ h, int N)
{
    const int tid   = threadIdx.x;
    const int wave  = tid >> 6;
    const int lane  = tid & 63;
    const int g     = lane >> 4;        // group 0..3 within wave
    const int gl    = lane & 15;        // lane in group
    const int slice = blockIdx.x & 7;
    const int row   = (blockIdx.x >> 3) * 16 + wave * 4 + g;
    if (row >= N) return;

    const int beg = rowptr[row];
    const int end = rowptr[row + 1];
    const size_t fofs = (size_t)slice * 32 + (size_t)gl * 2;

    half2v sv = *(const half2v*)(msg + (size_t)row * F_DIM + fofs);
    float a0 = (float)sv[0], a1 = (float)sv[1];

    int e = beg;
    for (; e + 2 <= end; e += 2) {
        const int s0 = csr_src[e];
        const int s1 = csr_src[e + 1];
        const half2v v0 = *(const half2v*)(msg + (size_t)s0 * F_DIM + fofs);
        const half2v v1 = *(const half2v*)(msg + (size_t)s1 * F_DIM + fofs);
        a0 += (float)v0[0] + (float)v1[0];
        a1 += (float)v0[1] + (float)v1[1];
    }
    if (e < end) {
        const int s0 = csr_src[e];
        const half2v v0 = *(const half2v*)(msg + (size_t)s0 * F_DIM + fofs);
        a0 += (float)v0[0];
        a1 += (float)v0[1];
    }

    half2v o;
    o[0] = (_Float16)fmaxf(a0, 0.f);
    o[1] = (_Float16)fmaxf(a1, 0.f);
    *(half2v*)(h + (size_t)row * F_DIM + fofs) = o;
}

// --- sparse PvT: out[prow[i]] += pval[i] * logits[pcol[i]], wave/nnz
__global__ __launch_bounds__(256) void pvt_scatter(
    const float* __restrict__ logits, const int* __restrict__ prow,
    const int* __restrict__ pcol, const float* __restrict__ pval,
    float* __restrict__ out, int nnz)
{
    const int i    = (blockIdx.x * 256 + threadIdx.x) >> 6;
    const int lane = threadIdx.x & 63;
    if (i >= nnz || lane >= C_DIM) return;
    const int r = prow[i];
    const int c = pcol[i];
    const float v = pval[i];
    atomicAdd(out + (size_t)r * C_DIM + lane, v * logits[(size_t)c * C_DIM + lane]);
}

// --- row-wise log_softmax in place, wave/row (lanes 0..39 active)
__global__ __launch_bounds__(256) void log_softmax40(float* __restrict__ out, int M)
{
    const int row  = (blockIdx.x * 256 + threadIdx.x) >> 6;
    const int lane = threadIdx.x & 63;
    if (row >= M) return;
    const float v = (lane < C_DIM) ? out[(size_t)row * C_DIM + lane] : -INFINITY;
    float m = v;
    #pragma unroll
    for (int off = 32; off >= 1; off >>= 1)
        m = fmaxf(m, __shfl_xor(m, off, 64));
    float e = (lane < C_DIM) ? expf(v - m) : 0.f;
    float s = e;
    #pragma unroll
    for (int off = 32; off >= 1; off >>= 1)
        s += __shfl_xor(s, off, 64);
    if (lane < C_DIM)
        out[(size_t)row * C_DIM + lane] = v - m - logf(s);
}

extern "C" void kernel_launch(void* const* d_in, const int* in_sizes, int n_in,
                              void* d_out, int out_size, void* d_ws, size_t ws_size,
                              hipStream_t stream)
{
    const float* x        = (const float*)d_in[0];
    const int*   edge_src = (const int*)d_in[1];
    const int*   edge_dst = (const int*)d_in[2];
    const int*   pvt_row  = (const int*)d_in[3];
    const int*   pvt_col  = (const int*)d_in[4];
    const float* pvt_val  = (const float*)d_in[5];
    const float* w1       = (const float*)d_in[6];
    const float* b1       = (const float*)d_in[7];
    const float* w2       = (const float*)d_in[8];
    const float* b2       = (const float*)d_in[9];
    const float* wfc      = (const float*)d_in[10];
    const float* bfc      = (const float*)d_in[11];

    const int N   = in_sizes[0] / F_DIM;   // 50000
    const int E   = in_sizes[1];           // 1600000
    const int NNZ = in_sizes[3];           // 50000

    float* out = (float*)d_out;

    // workspace layout
    const size_t nodeElems = (size_t)N * F_DIM;
    _Float16* w1t    = (_Float16*)d_ws;               // 256*256 fp16
    _Float16* w2t    = w1t + 65536;                   // 256*256 fp16
    _Float16* wfcT   = w2t + 65536;                   // 48*256 fp16
    _Float16* bufM   = wfcT + 48 * 256;               // msg, N*256 fp16
    _Float16* bufH   = bufM + nodeElems;              // h,   N*256 fp16
    float*    logits = (float*)(bufH + nodeElems);    // N x 40 f32
    int*      deg    = (int*)(logits + (size_t)N * C_DIM);
    int*      rowptr = deg + N;                       // N+1 ints
    int*      cursor = rowptr + N + 4;                // N ints
    int*      csr_src= cursor + N + 4;                // E ints

    const int partSize = (N + NPART - 1) / NPART;

    const dim3 gemmGrid((N + 127) / 128, 4);
    const int fcBlocks    = (N + 127) / 128;
    const int ePartBlocks = ((E + 255) / 256) * NPART;
    const int rowBlocks   = (N + 3) / 4;
    const int gatherBlocks= ((N + 15) / 16) * 8;      // 8 feature slices
    const int nnzBlocks   = (NNZ + 3) / 4;

    // === prep: weight conversions ===
    cvt_wT<<<256, 256, 0, stream>>>(w1, w1t);
    cvt_wT<<<256, 256, 0, stream>>>(w2, w2t);
    cvt_wfc<<<256, 48, 0, stream>>>(wfc, wfcT);

    // === CSR build (XCD-partitioned) ===
    hipMemsetAsync(deg, 0, (size_t)N * sizeof(int), stream);
    count_deg_part<<<ePartBlocks, 256, 0, stream>>>(edge_dst, deg, E, partSize);
    scan_deg4<<<1, 1024, 0, stream>>>(deg, rowptr, N);
    hipMemcpyAsync(cursor, rowptr, (size_t)N * sizeof(int),
                   hipMemcpyDeviceToDevice, stream);
    fill_csr_part<<<ePartBlocks, 256, 0, stream>>>(edge_src, edge_dst, cursor,
                                                   csr_src, E, partSize);

    // === layer 1 (A = fp32 x, converted in staging) ===
    gemm_f16<true><<<gemmGrid, 256, 0, stream>>>(x, w1t, b1, bufM, N);
    csr_gather_sliced<<<gatherBlocks, 256, 0, stream>>>(bufM, rowptr, csr_src, bufH, N);

    // === layer 2 ===
    gemm_f16<false><<<gemmGrid, 256, 0, stream>>>(bufH, w2t, b2, bufM, N);
    csr_gather_sliced<<<gatherBlocks, 256, 0, stream>>>(bufM, rowptr, csr_src, bufH, N);

    // === FC (MFMA) ===
    fc_mfma<<<fcBlocks, 256, 0, stream>>>(bufH, wfcT, bfc, logits, N);

    // === PvT scatter into d_out, then log_softmax ===
    hipMemsetAsync(d_out, 0, (size_t)N * C_DIM * sizeof(float), stream);
    pvt_scatter<<<nnzBlocks, 256, 0, stream>>>(logits, pvt_row, pvt_col, pvt_val, out, NNZ);
    log_softmax40<<<rowBlocks, 256, 0, stream>>>(out, N);
}

// Round 6
// 608.732 us; speedup vs baseline: 1.2840x; 1.2840x over previous
//
#include <hip/hip_runtime.h>
#include <hip/hip_bf16.h>
#include <math.h>

// ---------------------------------------------------------------------------
// MPNN node classifier.
// R5: revert feature-sliced gather (slicing didn't cut fabric traffic -- msg
// is LLC-resident; it only cut MLP, 3.68->2.18 TB/s). New gather: 2 rows per
// wave, half8 (16B) per lane over 32 lanes, edge loop unrolled x4 with
// independent loads. CSR build stays XCD-partitioned (R4).
// ---------------------------------------------------------------------------

#define F_DIM 256   // F_IN == H == 256
#define C_DIM 40
#define NPART 8

typedef _Float16 half8 __attribute__((ext_vector_type(8)));
typedef _Float16 half4 __attribute__((ext_vector_type(4)));
typedef float    f32x4 __attribute__((ext_vector_type(4)));

// --- convert + transpose weight: w[k][n] fp32 -> wt[n][k] fp16  (256x256)
__global__ __launch_bounds__(256) void cvt_wT(
    const float* __restrict__ w, _Float16* __restrict__ wt)
{
    const int n = threadIdx.x;
    const int k = blockIdx.x;
    wt[n * 256 + k] = (_Float16)w[k * 256 + n];
}

// --- convert + transpose + pad FC weight: wfc[k][40] fp32 -> wt[48][256] fp16
__global__ __launch_bounds__(48) void cvt_wfc(
    const float* __restrict__ wfc, _Float16* __restrict__ wt)
{
    const int n = threadIdx.x;   // 0..47
    const int k = blockIdx.x;    // 0..255
    wt[n * 256 + k] = (n < C_DIM) ? (_Float16)wfc[k * C_DIM + n] : (_Float16)0.f;
}

// --- MFMA fp16 GEMM: out[M x 256] = f16(relu(A[M x 256] @ Wt^T + bias))
template <bool AF32>
__global__ __launch_bounds__(256, 2) void gemm_f16(
    const void* __restrict__ Av, const _Float16* __restrict__ Wt,
    const float* __restrict__ bias, _Float16* __restrict__ out, int M)
{
    constexpr int K = 256;
    constexpr int LDA = 40;                 // padded fp16 stride: 2-way-free banks
    __shared__ _Float16 As[128 * LDA];
    __shared__ _Float16 Bs[64 * LDA];

    const int tid  = threadIdx.x;
    const int wave = tid >> 6;
    const int lane = tid & 63;
    const int quad = lane >> 4;
    const int l16  = lane & 15;
    const int row0 = blockIdx.x * 128;
    const int col0 = blockIdx.y * 64;

    f32x4 acc[2][4] = {};

    for (int k0 = 0; k0 < K; k0 += 32) {
        #pragma unroll
        for (int c = tid; c < 512; c += 256) {
            const int r  = c >> 2;
            const int ko = (c & 3) * 8;
            const int gr = row0 + r;
            half8 v = {};
            if (gr < M) {
                if constexpr (AF32) {
                    const float* A = (const float*)Av;
                    const float4 u0 = *(const float4*)(A + (size_t)gr * K + k0 + ko);
                    const float4 u1 = *(const float4*)(A + (size_t)gr * K + k0 + ko + 4);
                    v[0] = (_Float16)u0.x; v[1] = (_Float16)u0.y;
                    v[2] = (_Float16)u0.z; v[3] = (_Float16)u0.w;
                    v[4] = (_Float16)u1.x; v[5] = (_Float16)u1.y;
                    v[6] = (_Float16)u1.z; v[7] = (_Float16)u1.w;
                } else {
                    const _Float16* A = (const _Float16*)Av;
                    v = *(const half8*)(A + (size_t)gr * K + k0 + ko);
                }
            }
            *(half8*)&As[r * LDA + ko] = v;
        }
        {
            const int n  = tid >> 2;
            const int ko = (tid & 3) * 8;
            const half8 v = *(const half8*)(Wt + (size_t)(col0 + n) * K + k0 + ko);
            *(half8*)&Bs[n * LDA + ko] = v;
        }
        __syncthreads();

        half8 af[2], bf[4];
        #pragma unroll
        for (int mi = 0; mi < 2; ++mi)
            af[mi] = *(const half8*)&As[(wave * 32 + mi * 16 + l16) * LDA + quad * 8];
        #pragma unroll
        for (int ni = 0; ni < 4; ++ni)
            bf[ni] = *(const half8*)&Bs[(ni * 16 + l16) * LDA + quad * 8];
        #pragma unroll
        for (int mi = 0; mi < 2; ++mi)
            #pragma unroll
            for (int ni = 0; ni < 4; ++ni)
                acc[mi][ni] = __builtin_amdgcn_mfma_f32_16x16x32_f16(
                    af[mi], bf[ni], acc[mi][ni], 0, 0, 0);
        __syncthreads();
    }

    // epilogue: C/D layout col=lane&15, row=quad*4+reg
    #pragma unroll
    for (int ni = 0; ni < 4; ++ni) {
        const int col = col0 + ni * 16 + l16;
        const float b = bias[col];
        #pragma unroll
        for (int mi = 0; mi < 2; ++mi) {
            #pragma unroll
            for (int r = 0; r < 4; ++r) {
                const int grow = row0 + wave * 32 + mi * 16 + quad * 4 + r;
                if (grow < M) {
                    const float v = fmaxf(acc[mi][ni][r] + b, 0.f);
                    out[(size_t)grow * K + col] = (_Float16)v;
                }
            }
        }
    }
}

// --- MFMA FC: logits[M x 40] = h[M x 256] @ wfcT^T + bfc  (no relu)
__global__ __launch_bounds__(256, 2) void fc_mfma(
    const _Float16* __restrict__ h, const _Float16* __restrict__ WfcT,
    const float* __restrict__ bfc, float* __restrict__ logits, int M)
{
    constexpr int K = 256;
    constexpr int LDA = 40;
    constexpr int LDB = 264;
    __shared__ _Float16 As[128 * LDA];
    __shared__ _Float16 Bs[48 * LDB];

    const int tid  = threadIdx.x;
    const int wave = tid >> 6;
    const int lane = tid & 63;
    const int quad = lane >> 4;
    const int l16  = lane & 15;
    const int row0 = blockIdx.x * 128;

    #pragma unroll
    for (int c = tid; c < 1536; c += 256) {
        const int n  = c >> 5;
        const int ko = (c & 31) * 8;
        *(half8*)&Bs[n * LDB + ko] = *(const half8*)(WfcT + (size_t)n * K + ko);
    }

    f32x4 acc[2][3] = {};

    for (int k0 = 0; k0 < K; k0 += 32) {
        #pragma unroll
        for (int c = tid; c < 512; c += 256) {
            const int r  = c >> 2;
            const int ko = (c & 3) * 8;
            const int gr = row0 + r;
            half8 v = {};
            if (gr < M) v = *(const half8*)(h + (size_t)gr * K + k0 + ko);
            *(half8*)&As[r * LDA + ko] = v;
        }
        __syncthreads();

        half8 af[2], bf[3];
        #pragma unroll
        for (int mi = 0; mi < 2; ++mi)
            af[mi] = *(const half8*)&As[(wave * 32 + mi * 16 + l16) * LDA + quad * 8];
        #pragma unroll
        for (int ni = 0; ni < 3; ++ni)
            bf[ni] = *(const half8*)&Bs[(ni * 16 + l16) * LDB + k0 + quad * 8];
        #pragma unroll
        for (int mi = 0; mi < 2; ++mi)
            #pragma unroll
            for (int ni = 0; ni < 3; ++ni)
                acc[mi][ni] = __builtin_amdgcn_mfma_f32_16x16x32_f16(
                    af[mi], bf[ni], acc[mi][ni], 0, 0, 0);
        __syncthreads();
    }

    #pragma unroll
    for (int ni = 0; ni < 3; ++ni) {
        const int col = ni * 16 + l16;
        if (col >= C_DIM) continue;
        const float b = bfc[col];
        #pragma unroll
        for (int mi = 0; mi < 2; ++mi) {
            #pragma unroll
            for (int r = 0; r < 4; ++r) {
                const int grow = row0 + wave * 32 + mi * 16 + quad * 4 + r;
                if (grow < M)
                    logits[(size_t)grow * C_DIM + col] = acc[mi][ni][r] + b;
            }
        }
    }
}

// --- CSR build step 1: degree histogram, XCD-partitioned by dst range
__global__ __launch_bounds__(256) void count_deg_part(
    const int* __restrict__ dst, int* __restrict__ deg, int E, int partSize)
{
    const int part  = blockIdx.x & (NPART - 1);
    const int chunk = blockIdx.x >> 3;
    const int i = chunk * 256 + threadIdx.x;
    if (i >= E) return;
    const int d = dst[i];
    const int lo = part * partSize;
    if (d < lo || d >= lo + partSize) return;
    atomicAdd(&deg[d], 1);
}

// --- CSR build step 2: exclusive scan, int4 per thread (single workgroup)
__global__ __launch_bounds__(1024) void scan_deg4(
    const int* __restrict__ deg, int* __restrict__ rowptr, int N)
{
    __shared__ int waveSums[16];
    __shared__ int carrySh;
    const int tid  = threadIdx.x;
    const int lane = tid & 63;
    const int wid  = tid >> 6;
    const int N4 = N >> 2;                  // N divisible by 4
    if (tid == 0) carrySh = 0;
    __syncthreads();
    for (int base = 0; base < N4; base += 1024) {
        const int i4 = base + tid;
        int4 v = make_int4(0, 0, 0, 0);
        if (i4 < N4) v = ((const int4*)deg)[i4];
        const int tsum = v.x + v.y + v.z + v.w;
        int s = tsum;
        #pragma unroll
        for (int off = 1; off < 64; off <<= 1) {
            const int t = __shfl_up(s, off, 64);
            if (lane >= off) s += t;
        }
        if (lane == 63) waveSums[wid] = s;
        __syncthreads();
        if (wid == 0) {
            const int ws = (lane < 16) ? waveSums[lane] : 0;
            int ss = ws;
            #pragma unroll
            for (int off = 1; off < 16; off <<= 1) {
                const int t = __shfl_up(ss, off, 64);
                if (lane >= off) ss += t;
            }
            if (lane < 16) waveSums[lane] = ss - ws;   // exclusive
        }
        __syncthreads();
        const int carry = carrySh;
        if (i4 < N4) {
            const int e0 = carry + waveSums[wid] + (s - tsum);
            int4 o;
            o.x = e0;
            o.y = e0 + v.x;
            o.z = e0 + v.x + v.y;
            o.w = e0 + v.x + v.y + v.z;
            ((int4*)rowptr)[i4] = o;
        }
        __syncthreads();
        if (tid == 1023) carrySh = carry + waveSums[15] + s;
        __syncthreads();
    }
    if (tid == 0) rowptr[N] = carrySh;
}

// --- CSR build step 3: scatter src ids, XCD-partitioned by dst range
__global__ __launch_bounds__(256) void fill_csr_part(
    const int* __restrict__ src, const int* __restrict__ dst,
    int* __restrict__ cursor, int* __restrict__ csr_src, int E, int partSize)
{
    const int part  = blockIdx.x & (NPART - 1);
    const int chunk = blockIdx.x >> 3;
    const int i = chunk * 256 + threadIdx.x;
    if (i >= E) return;
    const int d = dst[i];
    const int lo = part * partSize;
    if (d < lo || d >= lo + partSize) return;
    const int pos = atomicAdd(&cursor[d], 1);
    csr_src[pos] = src[i];
}

// --- conv aggregate: h[row] = f16(relu(msg[row] + sum_{in-edges} msg[src]))
//     2 rows per wave: 32 lanes x half8 (16B) per row. Edge loop unrolled x4
//     with independent 16B loads for MLP. Shuffles stay within each 32-lane
//     group (safe under divergence between the two groups).
__global__ __launch_bounds__(256) void csr_gather_f16(
    const _Float16* __restrict__ msg, const int* __restrict__ rowptr,
    const int* __restrict__ csr_src, _Float16* __restrict__ h, int N)
{
    const int tid  = threadIdx.x;
    const int wave = tid >> 6;
    const int lane = tid & 63;
    const int g    = lane >> 5;              // row within wave (0/1)
    const int rl   = lane & 31;              // lane within row-group
    const int gsrc = lane & 32;              // shuffle base of this group
    const int row  = (blockIdx.x * 4 + wave) * 2 + g;
    if (row >= N) return;

    const int beg = rowptr[row];
    const int end = rowptr[row + 1];
    const size_t fofs = (size_t)rl * 8;

    const half8 self = *(const half8*)(msg + (size_t)row * F_DIM + fofs);
    float a[8];
    #pragma unroll
    for (int i = 0; i < 8; ++i) a[i] = (float)self[i];

    for (int e0 = beg; e0 < end; e0 += 32) {
        const int n  = min(32, end - e0);
        const int sv = (e0 + rl < end) ? csr_src[e0 + rl] : 0;
        int j = 0;
        for (; j + 4 <= n; j += 4) {
            const int s0 = __shfl(sv, gsrc + j + 0, 64);
            const int s1 = __shfl(sv, gsrc + j + 1, 64);
            const int s2 = __shfl(sv, gsrc + j + 2, 64);
            const int s3 = __shfl(sv, gsrc + j + 3, 64);
            const half8 v0 = *(const half8*)(msg + (size_t)s0 * F_DIM + fofs);
            const half8 v1 = *(const half8*)(msg + (size_t)s1 * F_DIM + fofs);
            const half8 v2 = *(const half8*)(msg + (size_t)s2 * F_DIM + fofs);
            const half8 v3 = *(const half8*)(msg + (size_t)s3 * F_DIM + fofs);
            #pragma unroll
            for (int i = 0; i < 8; ++i)
                a[i] += ((float)v0[i] + (float)v1[i]) + ((float)v2[i] + (float)v3[i]);
        }
        for (; j < n; ++j) {
            const int s = __shfl(sv, gsrc + j, 64);
            const half8 v = *(const half8*)(msg + (size_t)s * F_DIM + fofs);
            #pragma unroll
            for (int i = 0; i < 8; ++i) a[i] += (float)v[i];
        }
    }

    half8 o;
    #pragma unroll
    for (int i = 0; i < 8; ++i) o[i] = (_Float16)fmaxf(a[i], 0.f);
    *(half8*)(h + (size_t)row * F_DIM + fofs) = o;
}

// --- sparse PvT: out[prow[i]] += pval[i] * logits[pcol[i]], wave/nnz
__global__ __launch_bounds__(256) void pvt_scatter(
    const float* __restrict__ logits, const int* __restrict__ prow,
    const int* __restrict__ pcol, const float* __restrict__ pval,
    float* __restrict__ out, int nnz)
{
    const int i    = (blockIdx.x * 256 + threadIdx.x) >> 6;
    const int lane = threadIdx.x & 63;
    if (i >= nnz || lane >= C_DIM) return;
    const int r = prow[i];
    const int c = pcol[i];
    const float v = pval[i];
    atomicAdd(out + (size_t)r * C_DIM + lane, v * logits[(size_t)c * C_DIM + lane]);
}

// --- row-wise log_softmax in place, wave/row (lanes 0..39 active)
__global__ __launch_bounds__(256) void log_softmax40(float* __restrict__ out, int M)
{
    const int row  = (blockIdx.x * 256 + threadIdx.x) >> 6;
    const int lane = threadIdx.x & 63;
    if (row >= M) return;
    const float v = (lane < C_DIM) ? out[(size_t)row * C_DIM + lane] : -INFINITY;
    float m = v;
    #pragma unroll
    for (int off = 32; off >= 1; off >>= 1)
        m = fmaxf(m, __shfl_xor(m, off, 64));
    float e = (lane < C_DIM) ? expf(v - m) : 0.f;
    float s = e;
    #pragma unroll
    for (int off = 32; off >= 1; off >>= 1)
        s += __shfl_xor(s, off, 64);
    if (lane < C_DIM)
        out[(size_t)row * C_DIM + lane] = v - m - logf(s);
}

extern "C" void kernel_launch(void* const* d_in, const int* in_sizes, int n_in,
                              void* d_out, int out_size, void* d_ws, size_t ws_size,
                              hipStream_t stream)
{
    const float* x        = (const float*)d_in[0];
    const int*   edge_src = (const int*)d_in[1];
    const int*   edge_dst = (const int*)d_in[2];
    const int*   pvt_row  = (const int*)d_in[3];
    const int*   pvt_col  = (const int*)d_in[4];
    const float* pvt_val  = (const float*)d_in[5];
    const float* w1       = (const float*)d_in[6];
    const float* b1       = (const float*)d_in[7];
    const float* w2       = (const float*)d_in[8];
    const float* b2       = (const float*)d_in[9];
    const float* wfc      = (const float*)d_in[10];
    const float* bfc      = (const float*)d_in[11];

    const int N   = in_sizes[0] / F_DIM;   // 50000
    const int E   = in_sizes[1];           // 1600000
    const int NNZ = in_sizes[3];           // 50000

    float* out = (float*)d_out;

    // workspace layout
    const size_t nodeElems = (size_t)N * F_DIM;
    _Float16* w1t    = (_Float16*)d_ws;               // 256*256 fp16
    _Float16* w2t    = w1t + 65536;                   // 256*256 fp16
    _Float16* wfcT   = w2t + 65536;                   // 48*256 fp16
    _Float16* bufM   = wfcT + 48 * 256;               // msg, N*256 fp16
    _Float16* bufH   = bufM + nodeElems;              // h,   N*256 fp16
    float*    logits = (float*)(bufH + nodeElems);    // N x 40 f32
    int*      deg    = (int*)(logits + (size_t)N * C_DIM);
    int*      rowptr = deg + N;                       // N+1 ints
    int*      cursor = rowptr + N + 4;                // N ints
    int*      csr_src= cursor + N + 4;                // E ints

    const int partSize = (N + NPART - 1) / NPART;

    const dim3 gemmGrid((N + 127) / 128, 4);
    const int fcBlocks    = (N + 127) / 128;
    const int ePartBlocks = ((E + 255) / 256) * NPART;
    const int rowBlocks   = (N + 3) / 4;
    const int gatherBlocks= (N + 7) / 8;              // 8 rows per block
    const int nnzBlocks   = (NNZ + 3) / 4;

    // === prep: weight conversions ===
    cvt_wT<<<256, 256, 0, stream>>>(w1, w1t);
    cvt_wT<<<256, 256, 0, stream>>>(w2, w2t);
    cvt_wfc<<<256, 48, 0, stream>>>(wfc, wfcT);

    // === CSR build (XCD-partitioned) ===
    hipMemsetAsync(deg, 0, (size_t)N * sizeof(int), stream);
    count_deg_part<<<ePartBlocks, 256, 0, stream>>>(edge_dst, deg, E, partSize);
    scan_deg4<<<1, 1024, 0, stream>>>(deg, rowptr, N);
    hipMemcpyAsync(cursor, rowptr, (size_t)N * sizeof(int),
                   hipMemcpyDeviceToDevice, stream);
    fill_csr_part<<<ePartBlocks, 256, 0, stream>>>(edge_src, edge_dst, cursor,
                                                   csr_src, E, partSize);

    // === layer 1 (A = fp32 x, converted in staging) ===
    gemm_f16<true><<<gemmGrid, 256, 0, stream>>>(x, w1t, b1, bufM, N);
    csr_gather_f16<<<gatherBlocks, 256, 0, stream>>>(bufM, rowptr, csr_src, bufH, N);

    // === layer 2 ===
    gemm_f16<false><<<gemmGrid, 256, 0, stream>>>(bufH, w2t, b2, bufM, N);
    csr_gather_f16<<<gatherBlocks, 256, 0, stream>>>(bufM, rowptr, csr_src, bufH, N);

    // === FC (MFMA) ===
    fc_mfma<<<fcBlocks, 256, 0, stream>>>(bufH, wfcT, bfc, logits, N);

    // === PvT scatter into d_out, then log_softmax ===
    hipMemsetAsync(d_out, 0, (size_t)N * C_DIM * sizeof(float), stream);
    pvt_scatter<<<nnzBlocks, 256, 0, stream>>>(logits, pvt_row, pvt_col, pvt_val, out, NNZ);
    log_softmax40<<<rowBlocks, 256, 0, stream>>>(out, N);
}

// Round 7
// 584.013 us; speedup vs baseline: 1.3383x; 1.0423x over previous
//
#include <hip/hip_runtime.h>
#include <hip/hip_bf16.h>
#include <math.h>

// ---------------------------------------------------------------------------
// MPNN node classifier.
// R6: barrier-free GEMMs -- MFMA A-fragments load DIRECTLY from row-major
// global (lane=row, quad=k-offset covers 16 full 64B lines per instr), only
// B staged in LDS (once, padded). 128-col tiles halve A re-reads. Gather
// unrolled x8. scan writes cursor (drops memcpy dispatch).
// ---------------------------------------------------------------------------

#define F_DIM 256   // F_IN == H == 256
#define C_DIM 40
#define NPART 8

typedef _Float16 half8 __attribute__((ext_vector_type(8)));
typedef float    f32x4 __attribute__((ext_vector_type(4)));

// --- convert + transpose weight: w[k][n] fp32 -> wt[n][k] fp16  (256x256)
__global__ __launch_bounds__(256) void cvt_wT(
    const float* __restrict__ w, _Float16* __restrict__ wt)
{
    const int n = threadIdx.x;
    const int k = blockIdx.x;
    wt[n * 256 + k] = (_Float16)w[k * 256 + n];
}

// --- convert + transpose + pad FC weight: wfc[k][40] fp32 -> wt[48][256] fp16
__global__ __launch_bounds__(48) void cvt_wfc(
    const float* __restrict__ wfc, _Float16* __restrict__ wt)
{
    const int n = threadIdx.x;   // 0..47
    const int k = blockIdx.x;    // 0..255
    wt[n * 256 + k] = (n < C_DIM) ? (_Float16)wfc[k * C_DIM + n] : (_Float16)0.f;
}

// --- MFMA fp16 GEMM: out[M x 256] = f16(relu(A[M x 256] @ Wt^T + bias))
//     A row-major (fp32 if AF32 else fp16) read straight into MFMA A-frags
//     (no LDS, no K-loop barriers). B tile 128 cols x 256 K staged once.
//     Block: 128 rows x 128 cols, 4 waves (wave = 32 rows x 128 cols).
template <bool AF32>
__global__ __launch_bounds__(256, 2) void gemm_f16(
    const void* __restrict__ Av, const _Float16* __restrict__ Wt,
    const float* __restrict__ bias, _Float16* __restrict__ out, int M)
{
    constexpr int K = 256;
    constexpr int LDB = 264;                // 132 words ≡ 4 mod 32: conflict-free
    __shared__ _Float16 Bs[128 * LDB];

    const int tid  = threadIdx.x;
    const int wave = tid >> 6;
    const int lane = tid & 63;
    const int quad = lane >> 4;
    const int l16  = lane & 15;
    const int row0 = blockIdx.x * 128;
    const int col0 = blockIdx.y * 128;

    // stage B tile [128 n][256 k] once (coalesced; 16 chunks/thread)
    #pragma unroll
    for (int c = 0; c < 16; ++c) {
        const int idx = c * 256 + tid;
        const int n   = idx >> 5;
        const int ko  = (idx & 31) * 8;
        *(half8*)&Bs[n * LDB + ko] = *(const half8*)(Wt + (size_t)(col0 + n) * K + ko);
    }
    __syncthreads();

    const int gr0 = min(row0 + wave * 32 + l16,      M - 1);
    const int gr1 = min(row0 + wave * 32 + 16 + l16, M - 1);

    f32x4 acc[2][8] = {};

    for (int k0 = 0; k0 < K; k0 += 32) {
        half8 af[2];
        if constexpr (AF32) {
            const float* A = (const float*)Av;
            #pragma unroll
            for (int mi = 0; mi < 2; ++mi) {
                const int gr = mi ? gr1 : gr0;
                const float4 u0 = *(const float4*)(A + (size_t)gr * K + k0 + quad * 8);
                const float4 u1 = *(const float4*)(A + (size_t)gr * K + k0 + quad * 8 + 4);
                af[mi][0] = (_Float16)u0.x; af[mi][1] = (_Float16)u0.y;
                af[mi][2] = (_Float16)u0.z; af[mi][3] = (_Float16)u0.w;
                af[mi][4] = (_Float16)u1.x; af[mi][5] = (_Float16)u1.y;
                af[mi][6] = (_Float16)u1.z; af[mi][7] = (_Float16)u1.w;
            }
        } else {
            const _Float16* A = (const _Float16*)Av;
            af[0] = *(const half8*)(A + (size_t)gr0 * K + k0 + quad * 8);
            af[1] = *(const half8*)(A + (size_t)gr1 * K + k0 + quad * 8);
        }
        #pragma unroll
        for (int ni = 0; ni < 8; ++ni) {
            const half8 bf = *(const half8*)&Bs[(ni * 16 + l16) * LDB + k0 + quad * 8];
            acc[0][ni] = __builtin_amdgcn_mfma_f32_16x16x32_f16(af[0], bf, acc[0][ni], 0, 0, 0);
            acc[1][ni] = __builtin_amdgcn_mfma_f32_16x16x32_f16(af[1], bf, acc[1][ni], 0, 0, 0);
        }
    }

    // epilogue: C/D layout col=lane&15, row=quad*4+reg
    #pragma unroll
    for (int ni = 0; ni < 8; ++ni) {
        const int col = col0 + ni * 16 + l16;
        const float b = bias[col];
        #pragma unroll
        for (int mi = 0; mi < 2; ++mi) {
            #pragma unroll
            for (int r = 0; r < 4; ++r) {
                const int grow = row0 + wave * 32 + mi * 16 + quad * 4 + r;
                if (grow < M) {
                    const float v = fmaxf(acc[mi][ni][r] + b, 0.f);
                    out[(size_t)grow * K + col] = (_Float16)v;
                }
            }
        }
    }
}

// --- MFMA FC: logits[M x 40] = h[M x 256] @ wfcT^T + bfc  (no relu)
//     Same barrier-free scheme: Bs [48][256] staged once, A direct-global.
__global__ __launch_bounds__(256, 2) void fc_mfma(
    const _Float16* __restrict__ h, const _Float16* __restrict__ WfcT,
    const float* __restrict__ bfc, float* __restrict__ logits, int M)
{
    constexpr int K = 256;
    constexpr int LDB = 264;
    __shared__ _Float16 Bs[48 * LDB];

    const int tid  = threadIdx.x;
    const int wave = tid >> 6;
    const int lane = tid & 63;
    const int quad = lane >> 4;
    const int l16  = lane & 15;
    const int row0 = blockIdx.x * 128;

    #pragma unroll
    for (int c = 0; c < 6; ++c) {
        const int idx = c * 256 + tid;
        const int n   = idx >> 5;
        const int ko  = (idx & 31) * 8;
        *(half8*)&Bs[n * LDB + ko] = *(const half8*)(WfcT + (size_t)n * K + ko);
    }
    __syncthreads();

    const int gr0 = min(row0 + wave * 32 + l16,      M - 1);
    const int gr1 = min(row0 + wave * 32 + 16 + l16, M - 1);

    f32x4 acc[2][3] = {};

    for (int k0 = 0; k0 < K; k0 += 32) {
        half8 af[2];
        af[0] = *(const half8*)(h + (size_t)gr0 * K + k0 + quad * 8);
        af[1] = *(const half8*)(h + (size_t)gr1 * K + k0 + quad * 8);
        #pragma unroll
        for (int ni = 0; ni < 3; ++ni) {
            const half8 bf = *(const half8*)&Bs[(ni * 16 + l16) * LDB + k0 + quad * 8];
            acc[0][ni] = __builtin_amdgcn_mfma_f32_16x16x32_f16(af[0], bf, acc[0][ni], 0, 0, 0);
            acc[1][ni] = __builtin_amdgcn_mfma_f32_16x16x32_f16(af[1], bf, acc[1][ni], 0, 0, 0);
        }
    }

    #pragma unroll
    for (int ni = 0; ni < 3; ++ni) {
        const int col = ni * 16 + l16;
        if (col >= C_DIM) continue;
        const float b = bfc[col];
        #pragma unroll
        for (int mi = 0; mi < 2; ++mi) {
            #pragma unroll
            for (int r = 0; r < 4; ++r) {
                const int grow = row0 + wave * 32 + mi * 16 + quad * 4 + r;
                if (grow < M)
                    logits[(size_t)grow * C_DIM + col] = acc[mi][ni][r] + b;
            }
        }
    }
}

// --- CSR build step 1: degree histogram, XCD-partitioned by dst range
__global__ __launch_bounds__(256) void count_deg_part(
    const int* __restrict__ dst, int* __restrict__ deg, int E, int partSize)
{
    const int part  = blockIdx.x & (NPART - 1);
    const int chunk = blockIdx.x >> 3;
    const int i = chunk * 256 + threadIdx.x;
    if (i >= E) return;
    const int d = dst[i];
    const int lo = part * partSize;
    if (d < lo || d >= lo + partSize) return;
    atomicAdd(&deg[d], 1);
}

// --- CSR build step 2: exclusive scan, int4/thread; writes rowptr AND cursor
__global__ __launch_bounds__(1024) void scan_deg4(
    const int* __restrict__ deg, int* __restrict__ rowptr,
    int* __restrict__ cursor, int N)
{
    __shared__ int waveSums[16];
    __shared__ int carrySh;
    const int tid  = threadIdx.x;
    const int lane = tid & 63;
    const int wid  = tid >> 6;
    const int N4 = N >> 2;                  // N divisible by 4
    if (tid == 0) carrySh = 0;
    __syncthreads();
    for (int base = 0; base < N4; base += 1024) {
        const int i4 = base + tid;
        int4 v = make_int4(0, 0, 0, 0);
        if (i4 < N4) v = ((const int4*)deg)[i4];
        const int tsum = v.x + v.y + v.z + v.w;
        int s = tsum;
        #pragma unroll
        for (int off = 1; off < 64; off <<= 1) {
            const int t = __shfl_up(s, off, 64);
            if (lane >= off) s += t;
        }
        if (lane == 63) waveSums[wid] = s;
        __syncthreads();
        if (wid == 0) {
            const int ws = (lane < 16) ? waveSums[lane] : 0;
            int ss = ws;
            #pragma unroll
            for (int off = 1; off < 16; off <<= 1) {
                const int t = __shfl_up(ss, off, 64);
                if (lane >= off) ss += t;
            }
            if (lane < 16) waveSums[lane] = ss - ws;   // exclusive
        }
        __syncthreads();
        const int carry = carrySh;
        if (i4 < N4) {
            const int e0 = carry + waveSums[wid] + (s - tsum);
            int4 o;
            o.x = e0;
            o.y = e0 + v.x;
            o.z = e0 + v.x + v.y;
            o.w = e0 + v.x + v.y + v.z;
            ((int4*)rowptr)[i4] = o;
            ((int4*)cursor)[i4] = o;
        }
        __syncthreads();
        if (tid == 1023) carrySh = carry + waveSums[15] + s;
        __syncthreads();
    }
    if (tid == 0) rowptr[N] = carrySh;
}

// --- CSR build step 3: scatter src ids, XCD-partitioned by dst range
__global__ __launch_bounds__(256) void fill_csr_part(
    const int* __restrict__ src, const int* __restrict__ dst,
    int* __restrict__ cursor, int* __restrict__ csr_src, int E, int partSize)
{
    const int part  = blockIdx.x & (NPART - 1);
    const int chunk = blockIdx.x >> 3;
    const int i = chunk * 256 + threadIdx.x;
    if (i >= E) return;
    const int d = dst[i];
    const int lo = part * partSize;
    if (d < lo || d >= lo + partSize) return;
    const int pos = atomicAdd(&cursor[d], 1);
    csr_src[pos] = src[i];
}

// --- conv aggregate: h[row] = f16(relu(msg[row] + sum_{in-edges} msg[src]))
//     2 rows per wave (32 lanes x half8 each); edge loop unrolled x8 with
//     independent 16B loads for MLP.
__global__ __launch_bounds__(256) void csr_gather_f16(
    const _Float16* __restrict__ msg, const int* __restrict__ rowptr,
    const int* __restrict__ csr_src, _Float16* __restrict__ h, int N)
{
    const int tid  = threadIdx.x;
    const int wave = tid >> 6;
    const int lane = tid & 63;
    const int g    = lane >> 5;              // row within wave (0/1)
    const int rl   = lane & 31;              // lane within row-group
    const int gsrc = lane & 32;              // shuffle base of this group
    const int row  = (blockIdx.x * 4 + wave) * 2 + g;
    if (row >= N) return;

    const int beg = rowptr[row];
    const int end = rowptr[row + 1];
    const size_t fofs = (size_t)rl * 8;

    const half8 self = *(const half8*)(msg + (size_t)row * F_DIM + fofs);
    float a[8];
    #pragma unroll
    for (int i = 0; i < 8; ++i) a[i] = (float)self[i];

    for (int e0 = beg; e0 < end; e0 += 32) {
        const int n  = min(32, end - e0);
        const int sv = (e0 + rl < end) ? csr_src[e0 + rl] : 0;
        int j = 0;
        for (; j + 8 <= n; j += 8) {
            int s[8];
            #pragma unroll
            for (int u = 0; u < 8; ++u) s[u] = __shfl(sv, gsrc + j + u, 64);
            half8 v[8];
            #pragma unroll
            for (int u = 0; u < 8; ++u)
                v[u] = *(const half8*)(msg + (size_t)s[u] * F_DIM + fofs);
            #pragma unroll
            for (int u = 0; u < 8; ++u)
                #pragma unroll
                for (int i = 0; i < 8; ++i) a[i] += (float)v[u][i];
        }
        for (; j < n; ++j) {
            const int s = __shfl(sv, gsrc + j, 64);
            const half8 v = *(const half8*)(msg + (size_t)s * F_DIM + fofs);
            #pragma unroll
            for (int i = 0; i < 8; ++i) a[i] += (float)v[i];
        }
    }

    half8 o;
    #pragma unroll
    for (int i = 0; i < 8; ++i) o[i] = (_Float16)fmaxf(a[i], 0.f);
    *(half8*)(h + (size_t)row * F_DIM + fofs) = o;
}

// --- sparse PvT: out[prow[i]] += pval[i] * logits[pcol[i]], wave/nnz
__global__ __launch_bounds__(256) void pvt_scatter(
    const float* __restrict__ logits, const int* __restrict__ prow,
    const int* __restrict__ pcol, const float* __restrict__ pval,
    float* __restrict__ out, int nnz)
{
    const int i    = (blockIdx.x * 256 + threadIdx.x) >> 6;
    const int lane = threadIdx.x & 63;
    if (i >= nnz || lane >= C_DIM) return;
    const int r = prow[i];
    const int c = pcol[i];
    const float v = pval[i];
    atomicAdd(out + (size_t)r * C_DIM + lane, v * logits[(size_t)c * C_DIM + lane]);
}

// --- row-wise log_softmax in place, wave/row (lanes 0..39 active)
__global__ __launch_bounds__(256) void log_softmax40(float* __restrict__ out, int M)
{
    const int row  = (blockIdx.x * 256 + threadIdx.x) >> 6;
    const int lane = threadIdx.x & 63;
    if (row >= M) return;
    const float v = (lane < C_DIM) ? out[(size_t)row * C_DIM + lane] : -INFINITY;
    float m = v;
    #pragma unroll
    for (int off = 32; off >= 1; off >>= 1)
        m = fmaxf(m, __shfl_xor(m, off, 64));
    float e = (lane < C_DIM) ? expf(v - m) : 0.f;
    float s = e;
    #pragma unroll
    for (int off = 32; off >= 1; off >>= 1)
        s += __shfl_xor(s, off, 64);
    if (lane < C_DIM)
        out[(size_t)row * C_DIM + lane] = v - m - logf(s);
}

extern "C" void kernel_launch(void* const* d_in, const int* in_sizes, int n_in,
                              void* d_out, int out_size, void* d_ws, size_t ws_size,
                              hipStream_t stream)
{
    const float* x        = (const float*)d_in[0];
    const int*   edge_src = (const int*)d_in[1];
    const int*   edge_dst = (const int*)d_in[2];
    const int*   pvt_row  = (const int*)d_in[3];
    const int*   pvt_col  = (const int*)d_in[4];
    const float* pvt_val  = (const float*)d_in[5];
    const float* w1       = (const float*)d_in[6];
    const float* b1       = (const float*)d_in[7];
    const float* w2       = (const float*)d_in[8];
    const float* b2       = (const float*)d_in[9];
    const float* wfc      = (const float*)d_in[10];
    const float* bfc      = (const float*)d_in[11];

    const int N   = in_sizes[0] / F_DIM;   // 50000
    const int E   = in_sizes[1];           // 1600000
    const int NNZ = in_sizes[3];           // 50000

    float* out = (float*)d_out;

    // workspace layout
    const size_t nodeElems = (size_t)N * F_DIM;
    _Float16* w1t    = (_Float16*)d_ws;               // 256*256 fp16
    _Float16* w2t    = w1t + 65536;                   // 256*256 fp16
    _Float16* wfcT   = w2t + 65536;                   // 48*256 fp16
    _Float16* bufM   = wfcT + 48 * 256;               // msg, N*256 fp16
    _Float16* bufH   = bufM + nodeElems;              // h,   N*256 fp16
    float*    logits = (float*)(bufH + nodeElems);    // N x 40 f32
    int*      deg    = (int*)(logits + (size_t)N * C_DIM);
    int*      rowptr = deg + N;                       // N+1 ints
    int*      cursor = rowptr + N + 4;                // N ints
    int*      csr_src= cursor + N + 4;                // E ints

    const int partSize = (N + NPART - 1) / NPART;

    const dim3 gemmGrid((N + 127) / 128, 2);
    const int fcBlocks    = (N + 127) / 128;
    const int ePartBlocks = ((E + 255) / 256) * NPART;
    const int rowBlocks   = (N + 3) / 4;
    const int gatherBlocks= (N + 7) / 8;              // 8 rows per block
    const int nnzBlocks   = (NNZ + 3) / 4;

    // === prep: weight conversions ===
    cvt_wT<<<256, 256, 0, stream>>>(w1, w1t);
    cvt_wT<<<256, 256, 0, stream>>>(w2, w2t);
    cvt_wfc<<<256, 48, 0, stream>>>(wfc, wfcT);

    // === CSR build (XCD-partitioned) ===
    hipMemsetAsync(deg, 0, (size_t)N * sizeof(int), stream);
    count_deg_part<<<ePartBlocks, 256, 0, stream>>>(edge_dst, deg, E, partSize);
    scan_deg4<<<1, 1024, 0, stream>>>(deg, rowptr, cursor, N);
    fill_csr_part<<<ePartBlocks, 256, 0, stream>>>(edge_src, edge_dst, cursor,
                                                   csr_src, E, partSize);

    // === layer 1 (A = fp32 x, converted inline) ===
    gemm_f16<true><<<gemmGrid, 256, 0, stream>>>(x, w1t, b1, bufM, N);
    csr_gather_f16<<<gatherBlocks, 256, 0, stream>>>(bufM, rowptr, csr_src, bufH, N);

    // === layer 2 ===
    gemm_f16<false><<<gemmGrid, 256, 0, stream>>>(bufH, w2t, b2, bufM, N);
    csr_gather_f16<<<gatherBlocks, 256, 0, stream>>>(bufM, rowptr, csr_src, bufH, N);

    // === FC (MFMA) ===
    fc_mfma<<<fcBlocks, 256, 0, stream>>>(bufH, wfcT, bfc, logits, N);

    // === PvT scatter into d_out, then log_softmax ===
    hipMemsetAsync(d_out, 0, (size_t)N * C_DIM * sizeof(float), stream);
    pvt_scatter<<<nnzBlocks, 256, 0, stream>>>(logits, pvt_row, pvt_col, pvt_val, out, NNZ);
    log_softmax40<<<rowBlocks, 256, 0, stream>>>(out, N);
}